// Round 1
// baseline (531.625 us; speedup 1.0000x reference)
//
#include <hip/hip_runtime.h>
#include <math.h>

#define EPSF 1e-6f
#define TCLIP (1.0f - 1e-5f)
#define NPTS 16384
#define DDIM 256
#define NBLK_SUM 128
#define PART_STRIDE 258
#define FRECHET_ITERS_N 10

// ws float layout:
// [0,256)   mu
// [256,512) om
// [512,528) scalars: 0=mu2 1=om2 2=omu 3=ratio(lam_mu/lam_om) 4=gamma 5=qo 6=qm 7=q2 8=lam_om
// [544, 544 + NBLK_SUM*PART_STRIDE) per-block partials (256 vec + 1 scalar + pad)
#define WS_MU 0
#define WS_OM 256
#define WS_SC 512
#define WS_PART 544

__device__ __forceinline__ float block_sum256(float v) {
    __shared__ float s_bs[4];
    #pragma unroll
    for (int off = 32; off; off >>= 1) v += __shfl_xor(v, off);
    const int w = threadIdx.x >> 6, l = threadIdx.x & 63;
    __syncthreads();                 // protect s_bs reuse across calls
    if (l == 0) s_bs[w] = v;
    __syncthreads();
    return s_bs[0] + s_bs[1] + s_bs[2] + s_bs[3];
}

// mode 0: plain sum of x_i          -> partial vec
// mode 1: sum s_i*B_i*x_i, s_i*A_i  -> partial vec + scalar
// mode 2: sum dist(x_i,mu)^2        -> partial scalar
__global__ __launch_bounds__(256) void sum_pass(
    const float* __restrict__ x, const float* __restrict__ Kp,
    const float* __restrict__ ws, float* __restrict__ part, int mode)
{
    const float c = -Kp[0];
    const float sc = sqrtf(c);
    const int lane = threadIdx.x & 63;
    const int wv = threadIdx.x >> 6;
    const int gw = blockIdx.x * 4 + wv;
    const int nw = gridDim.x * 4;          // 512 waves
    const int ppw = NPTS / nw;             // 32 points/wave, contiguous
    const int p0 = gw * ppw;

    float4 mu4 = make_float4(0.f, 0.f, 0.f, 0.f);
    float mu2 = 0.f;
    if (mode != 0) {
        mu4 = ((const float4*)(ws + WS_MU))[lane];
        mu2 = ws[WS_SC + 0];
    }
    float ax = 0.f, ay = 0.f, az = 0.f, aw = 0.f, accA = 0.f;

    for (int p = p0; p < p0 + ppw; ++p) {
        float4 x4 = ((const float4*)x)[p * 64 + lane];
        float y2 = x4.x * x4.x + x4.y * x4.y + x4.z * x4.z + x4.w * x4.w;
        float d  = mu4.x * x4.x + mu4.y * x4.y + mu4.z * x4.z + mu4.w * x4.w;
        #pragma unroll
        for (int off = 32; off; off >>= 1) {
            y2 += __shfl_xor(y2, off);
            d  += __shfl_xor(d, off);
        }
        if (mode == 0) {
            ax += x4.x; ay += x4.y; az += x4.z; aw += x4.w;
        } else {
            // m1 = mobius_add(-mu, x_i) = A*mu + B*x_i
            float P = 1.f - 2.f * c * d;
            float den = fmaxf(P + c * c * mu2 * y2, EPSF);
            float A = -(P + c * y2) / den;
            float B = (1.f - c * mu2) / den;
            float mn2 = fmaxf(A * A * mu2 + 2.f * A * B * d + B * B * y2, EPSF);
            float mn = sqrtf(mn2);
            float t = atanhf(fminf(sc * mn, TCLIP));
            if (mode == 1) {
                // s = (2/(sc*lam_mu)) * t / mn = clip(1-c*mu2)/sc * t/mn
                float s = (fmaxf(1.f - c * mu2, EPSF) / sc) * t / mn;
                float w = s * B;
                ax += w * x4.x; ay += w * x4.y; az += w * x4.z; aw += w * x4.w;
                accA += s * A;
            } else {
                float dd = (2.f / sc) * t;
                accA += dd * dd;
            }
        }
    }

    __shared__ float lds[4 * DDIM];
    __shared__ float ldsA[4];
    ((float4*)(lds + wv * DDIM))[lane] = make_float4(ax, ay, az, aw);
    if (lane == 0) ldsA[wv] = accA;    // accA is lane-uniform
    __syncthreads();
    const int t = threadIdx.x;
    float s = lds[t] + lds[DDIM + t] + lds[2 * DDIM + t] + lds[3 * DDIM + t];
    part[blockIdx.x * PART_STRIDE + t] = s;
    if (t == 0)
        part[blockIdx.x * PART_STRIDE + DDIM] = ldsA[0] + ldsA[1] + ldsA[2] + ldsA[3];
}

__global__ __launch_bounds__(256) void fin_init(
    const float* __restrict__ Kp, const float* __restrict__ mean_param,
    float* __restrict__ ws)
{
    const float c = -Kp[0];
    const float sc = sqrtf(c);
    const float* part = ws + WS_PART;
    const int t = threadIdx.x;

    float s = 0.f;
    for (int b = 0; b < NBLK_SUM; ++b) s += part[b * PART_STRIDE + t];
    float m = s * (1.f / NPTS);
    float mn2 = block_sum256(m * m);
    float mn = sqrtf(fmaxf(mn2, EPSF));
    float maxn = (1.f - 1e-3f) / sc;
    float f = fminf(1.f, maxn / mn);
    float mu = m * f;
    ws[WS_MU + t] = mu;
    float mu2 = block_sum256(mu * mu);
    if (t == 0) ws[WS_SC + 0] = mu2;

    // om = exp0(mean_param)
    float u = mean_param[t];
    float un2 = block_sum256(u * u);
    float un = sqrtf(fmaxf(un2, EPSF));
    float om = tanhf(sc * un) * u / (sc * un);
    ws[WS_OM + t] = om;
    float om2 = block_sum256(om * om);
    if (t == 0) ws[WS_SC + 1] = om2;
}

__global__ __launch_bounds__(256) void fin_iter(
    const float* __restrict__ Kp, float* __restrict__ ws)
{
    const float c = -Kp[0];
    const float sc = sqrtf(c);
    const float* part = ws + WS_PART;
    const int t = threadIdx.x;

    float s = 0.f, sA = 0.f;
    for (int b = 0; b < NBLK_SUM; ++b) {
        s  += part[b * PART_STRIDE + t];
        sA += part[b * PART_STRIDE + DDIM];
    }
    float mu = ws[WS_MU + t];
    float mu2 = ws[WS_SC + 0];
    float g = s * (1.f / NPTS) + (sA * (1.f / NPTS)) * mu;

    // mu' = expmap(mu, g)
    float gn2 = block_sum256(g * g);
    float mg  = block_sum256(mu * g);
    float un = sqrtf(fmaxf(gn2, EPSF));
    float lam = 2.f / fmaxf(1.f - c * mu2, EPSF);
    float k = tanhf(sc * lam * un * 0.5f) / (sc * un);
    float sec = k * g;
    float ms = k * mg;           // <mu, second>
    float s2 = k * k * gn2;      // ||second||^2 (raw)
    float a = 1.f + 2.f * c * ms + c * s2;
    float b = 1.f - c * mu2;
    float den = fmaxf(1.f + 2.f * c * ms + c * c * mu2 * s2, EPSF);
    float nmu = (a * mu + b * sec) / den;
    ws[WS_MU + t] = nmu;
    float nmu2 = block_sum256(nmu * nmu);
    if (t == 0) ws[WS_SC + 0] = nmu2;
}

__global__ __launch_bounds__(256) void fin_var(
    const float* __restrict__ Kp, const float* __restrict__ var_param,
    float* __restrict__ ws)
{
    const float c = -Kp[0];
    const float* part = ws + WS_PART;
    const int t = threadIdx.x;

    float sA = 0.f;
    for (int b = 0; b < NBLK_SUM; ++b) sA += part[b * PART_STRIDE + DDIM];
    float var = sA * (1.f / NPTS);
    float gamma = sqrtf(var_param[0] / (var + 1e-6f));

    float mu = ws[WS_MU + t], om = ws[WS_OM + t];
    float omu = block_sum256(om * mu);
    float mu2 = ws[WS_SC + 0], om2 = ws[WS_SC + 1];
    float Amu = fmaxf(1.f - c * mu2, EPSF);   // 2/lam_mu
    float Aom = fmaxf(1.f - c * om2, EPSF);   // 2/lam_om
    float ratio = Aom / Amu;                  // lam_mu/lam_om

    // q = mobius_add(om, -mu) = qo*om + qm*mu
    float aq = 1.f - 2.f * c * omu + c * mu2;
    float bq = 1.f - c * om2;
    float dq = fmaxf(1.f - 2.f * c * omu + c * c * om2 * mu2, EPSF);
    float qo = aq / dq, qm = -bq / dq;
    float q2 = qo * qo * om2 + 2.f * qo * qm * omu + qm * qm * mu2;

    if (t == 0) {
        ws[WS_SC + 2] = omu;
        ws[WS_SC + 3] = ratio;
        ws[WS_SC + 4] = gamma;
        ws[WS_SC + 5] = qo;
        ws[WS_SC + 6] = qm;
        ws[WS_SC + 7] = q2;
        ws[WS_SC + 8] = 2.f / Aom;   // lam_om
    }
}

__global__ __launch_bounds__(256) void out_pass(
    const float* __restrict__ x, const float* __restrict__ Kp,
    const float* __restrict__ ws, float* __restrict__ out)
{
    const float c = -Kp[0];
    const float sc = sqrtf(c);
    const int lane = threadIdx.x & 63;
    const int wv = threadIdx.x >> 6;
    const int gw = blockIdx.x * 4 + wv;
    const int nw = gridDim.x * 4;        // 1024 waves
    const int ppw = NPTS / nw;           // 16 points/wave
    const int p0 = gw * ppw;

    float4 mu4 = ((const float4*)(ws + WS_MU))[lane];
    float4 om4 = ((const float4*)(ws + WS_OM))[lane];
    const float mu2 = ws[WS_SC + 0], om2 = ws[WS_SC + 1], omu = ws[WS_SC + 2];
    const float ratio = ws[WS_SC + 3], gamma = ws[WS_SC + 4];
    const float qo = ws[WS_SC + 5], qm = ws[WS_SC + 6], q2 = ws[WS_SC + 7];
    const float lam_om = ws[WS_SC + 8];

    for (int p = p0; p < p0 + ppw; ++p) {
        float4 x4 = ((const float4*)x)[p * 64 + lane];
        float y2 = x4.x * x4.x + x4.y * x4.y + x4.z * x4.z + x4.w * x4.w;
        float d  = mu4.x * x4.x + mu4.y * x4.y + mu4.z * x4.z + mu4.w * x4.w;
        float e  = om4.x * x4.x + om4.y * x4.y + om4.z * x4.z + om4.w * x4.w;
        #pragma unroll
        for (int off = 32; off; off >>= 1) {
            y2 += __shfl_xor(y2, off);
            d  += __shfl_xor(d, off);
            e  += __shfl_xor(e, off);
        }

        // Gram helpers over basis (om, mu, x_i)
        auto dotOm = [&](float po, float pm, float px) { return po * om2 + pm * omu + px * e; };
        auto dotMu = [&](float po, float pm, float px) { return po * omu + pm * mu2 + px * d; };
        auto sqn3  = [&](float po, float pm, float px) {
            return po * po * om2 + pm * pm * mu2 + px * px * y2
                 + 2.f * (po * pm * omu + po * px * e + pm * px * d);
        };

        // u = logmap(mu, x_i) = Um*mu + Ux*x_i
        float P = 1.f - 2.f * c * d;
        float den0 = fmaxf(P + c * c * mu2 * y2, EPSF);
        float A = -(P + c * y2) / den0;
        float B = (1.f - c * mu2) / den0;
        float mn2 = fmaxf(A * A * mu2 + 2.f * A * B * d + B * B * y2, EPSF);
        float mn = sqrtf(mn2);
        float tt = atanhf(fminf(sc * mn, TCLIP));
        float s = (fmaxf(1.f - c * mu2, EPSF) / sc) * tt / mn;
        float Um = s * A, Ux = s * B;

        // h1 = mobius_add(-mu, u)
        float xy1 = -dotMu(0.f, Um, Ux);
        float Y21 = sqn3(0.f, Um, Ux);
        float a1 = 1.f + 2.f * c * xy1 + c * Y21;
        float b1 = 1.f - c * mu2;
        float dn1 = fmaxf(1.f + 2.f * c * xy1 + c * c * mu2 * Y21, EPSF);
        float h1m = (-a1 + b1 * Um) / dn1;
        float h1x = (b1 * Ux) / dn1;

        // h2 = mobius_add(om, h1)
        float xy2 = dotOm(0.f, h1m, h1x);
        float Y22 = sqn3(0.f, h1m, h1x);
        float a2 = 1.f + 2.f * c * xy2 + c * Y22;
        float b2 = 1.f - c * om2;
        float dn2 = fmaxf(1.f + 2.f * c * xy2 + c * c * om2 * Y22, EPSF);
        float h2o = a2 / dn2;
        float h2m = (b2 * h1m) / dn2;
        float h2x = (b2 * h1x) / dn2;

        // g2 = mobius_add(-q, h2), q = (qo, qm, 0)
        float xy3 = -(qo * dotOm(h2o, h2m, h2x) + qm * dotMu(h2o, h2m, h2x));
        float Y23 = sqn3(h2o, h2m, h2x);
        float a3 = 1.f + 2.f * c * xy3 + c * Y23;
        float b3 = 1.f - c * q2;
        float dn3 = fmaxf(1.f + 2.f * c * xy3 + c * c * q2 * Y23, EPSF);
        float g2o = (-a3 * qo + b3 * h2o) / dn3;
        float g2m = (-a3 * qm + b3 * h2m) / dn3;
        float g2x = (b3 * h2x) / dn3;

        // L = (lam_mu/lam_om)*gamma*g2 ; out = expmap(om, L)
        float k1 = ratio * gamma;
        float Lo = k1 * g2o, Lm = k1 * g2m, Lx = k1 * g2x;
        float un2 = sqn3(Lo, Lm, Lx);
        float un = sqrtf(fmaxf(un2, EPSF));
        float coef = tanhf(sc * lam_om * un * 0.5f) / (sc * un);
        float So = coef * Lo, Sm = coef * Lm, Sx = coef * Lx;
        float xy4 = dotOm(So, Sm, Sx);
        float Y24 = coef * coef * un2;
        float a4 = 1.f + 2.f * c * xy4 + c * Y24;
        float b4 = 1.f - c * om2;
        float dn4 = fmaxf(1.f + 2.f * c * xy4 + c * c * om2 * Y24, EPSF);
        float fo = (a4 + b4 * So) / dn4;
        float fm = (b4 * Sm) / dn4;
        float fx = (b4 * Sx) / dn4;

        float4 o4;
        o4.x = fo * om4.x + fm * mu4.x + fx * x4.x;
        o4.y = fo * om4.y + fm * mu4.y + fx * x4.y;
        o4.z = fo * om4.z + fm * mu4.z + fx * x4.z;
        o4.w = fo * om4.w + fm * mu4.w + fx * x4.w;
        ((float4*)out)[p * 64 + lane] = o4;
    }
}

extern "C" void kernel_launch(void* const* d_in, const int* in_sizes, int n_in,
                              void* d_out, int out_size, void* d_ws, size_t ws_size,
                              hipStream_t stream) {
    const float* x = (const float*)d_in[0];
    const float* K = (const float*)d_in[1];
    const float* mean_param = (const float*)d_in[2];
    const float* var_param = (const float*)d_in[3];
    float* out = (float*)d_out;
    float* ws = (float*)d_ws;
    float* part = ws + WS_PART;

    sum_pass<<<NBLK_SUM, 256, 0, stream>>>(x, K, ws, part, 0);
    fin_init<<<1, 256, 0, stream>>>(K, mean_param, ws);
    for (int i = 0; i < FRECHET_ITERS_N; ++i) {
        sum_pass<<<NBLK_SUM, 256, 0, stream>>>(x, K, ws, part, 1);
        fin_iter<<<1, 256, 0, stream>>>(K, ws);
    }
    sum_pass<<<NBLK_SUM, 256, 0, stream>>>(x, K, ws, part, 2);
    fin_var<<<1, 256, 0, stream>>>(K, var_param, ws);
    out_pass<<<256, 256, 0, stream>>>(x, K, ws, out);
}